// Round 11
// baseline (83.434 us; speedup 1.0000x reference)
//
#include <hip/hip_runtime.h>
#include <math.h>

// Problem constants (match reference setup_inputs)
#define NN 4096
#define MM 128
#define QQ 64
#define DD 128
#define CC (MM * QQ)          // 8192 gemm "columns" (flattened m,q)

typedef float f32x4 __attribute__((ext_vector_type(4)));
typedef int   i32x4 __attribute__((ext_vector_type(4)));
typedef int   i32x8 __attribute__((ext_vector_type(8)));

// ---- prep: fp32 -> fp8 e4m3 (OCP) convert + exact fp32 squared norms ----
// (verbatim R9: plain stores; cross-kernel visibility from dispatch boundary)
__global__ __launch_bounds__(256)
void prep_kernel(const float* __restrict__ A, const float* __restrict__ B,
                 unsigned char* __restrict__ A8, unsigned char* __restrict__ B8,
                 float* __restrict__ a2, float* __restrict__ b2)
{
    const int row = blockIdx.x * 8 + (threadIdx.x >> 5);    // 0..12287
    const int l32 = threadIdx.x & 31;
    const float* src;
    unsigned char* dst;
    float* nrm;
    if (row < NN) { src = A + (size_t)row * DD; dst = A8 + (size_t)row * DD; nrm = a2 + row; }
    else {
        int r = row - NN;
        src = B + (size_t)r * DD; dst = B8 + (size_t)r * DD; nrm = b2 + r;
    }
    float4 v = ((const float4*)src)[l32];
    int pk = __builtin_amdgcn_cvt_pk_fp8_f32(v.x, v.y, 0, false);   // bytes 0,1
    pk     = __builtin_amdgcn_cvt_pk_fp8_f32(v.z, v.w, pk, true);   // bytes 2,3
    ((int*)dst)[l32] = pk;
    float s = v.x * v.x + v.y * v.y + v.z * v.z + v.w * v.w;
    #pragma unroll
    for (int m = 16; m > 0; m >>= 1) s += __shfl_xor(s, m, 64);  // stays in 32-group
    if (l32 == 0) *nrm = s;
}

// ---- dens: ZERO-LDS pure register dataflow (R11).
// Theory: all prior variants paid the LDS staging apparatus (gload_lds ->
// barrier -> swizzled ds_read) for operands reused only 2x per block and
// fully L2-resident (A8+B8 = 1.5MB << 4MB/XCD after the XCD swizzle) --
// Common-mistake #7. Here each wave loads its 16 fragments DIRECTLY from
// global (independent 16B loads, L2 hits), 16 MFMAs, epilogue, store.
// No __shared__, no __syncthreads, 3 waves/SIMD, waves fully independent.
__global__ __launch_bounds__(256, 3)
void kde_dens_kernel(const unsigned char* __restrict__ A8,   // [NN][DD] fp8
                     const unsigned char* __restrict__ B8,   // [CC][DD] fp8
                     const float* __restrict__ var,
                     const float* __restrict__ a2w,          // [NN]
                     const float* __restrict__ b2w,          // [CC]
                     float* __restrict__ dpc)                // [MM][NN] transposed
{
    // XCD swizzle: XCD x owns cb in [8x, 8x+8) -> A8 (512KB) + its B8 slice
    // stay L2-resident per XCD
    const int lin = blockIdx.x;                 // 0..2047
    const int xcd = lin & 7;
    const int loc = lin >> 3;                   // 0..255
    const int cb  = (xcd << 3) | (loc & 7);     // 0..63
    const int nb  = loc >> 3;                   // 0..31
    const int n0  = nb * 128;
    const int c0  = cb * 128;

    const int t = threadIdx.x, w = t >> 6, lane = t & 63;
    const int l15 = lane & 15, q = lane >> 4;
    const int wy = w >> 1, wx = w & 1;
    const int rbase = wy * 64, cbase = wx * 64;
    const int m = (cb << 1) + wx;

    // ---- direct global fragment loads (all independent, issued up front) ----
    // lane needs row bytes [q*32, q*32+32) of 16 A-rows and 16 B-rows
    const unsigned char* Abase = A8 + (size_t)(n0 + rbase + l15) * DD + q * 32;
    const unsigned char* Bbase = B8 + (size_t)(c0 + cbase + l15) * DD + q * 32;
    i32x8 a8[4], b8v[4];
    #pragma unroll
    for (int i = 0; i < 4; ++i) {
        const i32x4 lo = *(const i32x4*)(Abase + (size_t)(i * 16) * DD);
        const i32x4 hi = *(const i32x4*)(Abase + (size_t)(i * 16) * DD + 16);
        #pragma unroll
        for (int e = 0; e < 4; ++e) { a8[i][e] = lo[e]; a8[i][4 + e] = hi[e]; }
    }
    #pragma unroll
    for (int jc = 0; jc < 4; ++jc) {
        const i32x4 lo = *(const i32x4*)(Bbase + (size_t)(jc * 16) * DD);
        const i32x4 hi = *(const i32x4*)(Bbase + (size_t)(jc * 16) * DD + 16);
        #pragma unroll
        for (int e = 0; e < 4; ++e) { b8v[jc][e] = lo[e]; b8v[jc][4 + e] = hi[e]; }
    }

    const float hinvL = (0.5f / var[0]) * 1.44269504088896f;  // 0.5/var * log2(e)
    const float h2L   = hinvL + hinvL;

    // c-side factors direct from global (16B vector loads, L2 hits)
    f32x4 nbh[4];
    #pragma unroll
    for (int jc = 0; jc < 4; ++jc) {
        const f32x4 bv = *(const f32x4*)&b2w[c0 + cbase + jc * 16 + q * 4];
        nbh[jc] = -bv * hinvL;
    }

    // Swapped operands -> c-reduction in-register. 16 independent MFMAs.
    f32x4 acc[4][4] = {};
    #pragma unroll
    for (int jc = 0; jc < 4; ++jc)
        #pragma unroll
        for (int i = 0; i < 4; ++i)
            acc[jc][i] = __builtin_amdgcn_mfma_scale_f32_16x16x128_f8f6f4(
                            b8v[jc], a8[i], acc[jc][i],
                            0, 0,          // cbsz=0 (fp8), blgp=0 (fp8)
                            0, 127,        // scale_a = 1.0
                            0, 127);       // scale_b = 1.0

    // epilogue: dens = exp2(log2e*(2ab - a2 - b2)*0.5/var);
    // 16 c lane-local -> 2 partial chains + 4-way over q (2 shfl_xor).
    // Identical math/order to verified R9.
    float sums[4];
    #pragma unroll
    for (int i = 0; i < 4; ++i) {
        const float aih = a2w[n0 + rbase + i * 16 + l15] * hinvL;
        float s0 = 0.f, s1 = 0.f;
        #pragma unroll
        for (int jc = 0; jc < 4; jc += 2) {
            #pragma unroll
            for (int r = 0; r < 4; ++r) {
                s0 += __builtin_amdgcn_exp2f(fmaf(h2L, acc[jc][i][r],     nbh[jc][r]     - aih));
                s1 += __builtin_amdgcn_exp2f(fmaf(h2L, acc[jc + 1][i][r], nbh[jc + 1][r] - aih));
            }
        }
        float s = s0 + s1;
        s += __shfl_xor(s, 16, 64);
        s += __shfl_xor(s, 32, 64);
        sums[i] = s;   // full 64-col sum for n = rbase + i*16 + l15
    }
    // lane owns n = rbase + lane (i == q); static select; coalesced store
    const float v01 = (q & 1) ? sums[1] : sums[0];
    const float v23 = (q & 1) ? sums[3] : sums[2];
    const float myv = (q & 2) ? v23 : v01;
    dpc[(size_t)m * NN + n0 + rbase + lane] = myv;
}

// ---- normalize: out[n,m] = dpc[m,n] / (sum_m dpc[:,n] + 1e-10) ----
// (verbatim R9: 256 blocks x 16 n; m-ascending sum order)
__global__ __launch_bounds__(256)
void kde_norm_kernel(const float* __restrict__ dpc, float* __restrict__ out)
{
    __shared__ float tile[128][17];    // [m][nloc], odd stride
    __shared__ float rden[16];
    const int n0 = blockIdx.x * 16;
    const int t  = threadIdx.x;

    const int mr = t >> 1, half = t & 1;   // 128 rows x 2 threads
    {
        const float4 va = *(const float4*)&dpc[(size_t)mr * NN + n0 + half * 8];
        const float4 vb = *(const float4*)&dpc[(size_t)mr * NN + n0 + half * 8 + 4];
        float* tr = &tile[mr][half * 8];
        tr[0] = va.x; tr[1] = va.y; tr[2] = va.z; tr[3] = va.w;
        tr[4] = vb.x; tr[5] = vb.y; tr[6] = vb.z; tr[7] = vb.w;
    }
    __syncthreads();

    if (t < 16) {
        float s = 0.f;
        #pragma unroll 8
        for (int mm = 0; mm < MM; ++mm) s += tile[mm][t];   // m ascending, matches ref
        rden[t] = 1.f / (s + 1e-10f);
    }
    __syncthreads();

    const int j = t >> 4, m0 = (t & 15) * 8;
    const float r = rden[j];
    float4 o0, o1;
    o0.x = tile[m0][j] * r;     o0.y = tile[m0 + 1][j] * r;
    o0.z = tile[m0 + 2][j] * r; o0.w = tile[m0 + 3][j] * r;
    o1.x = tile[m0 + 4][j] * r; o1.y = tile[m0 + 5][j] * r;
    o1.z = tile[m0 + 6][j] * r; o1.w = tile[m0 + 7][j] * r;
    float* obase = &out[(size_t)(n0 + j) * MM + m0];
    *(float4*)obase       = o0;
    *(float4*)(obase + 4) = o1;   // 512B per 16-thread group, coalesced
}

extern "C" void kernel_launch(void* const* d_in, const int* in_sizes, int n_in,
                              void* d_out, int out_size, void* d_ws, size_t ws_size,
                              hipStream_t stream) {
    const float* A   = (const float*)d_in[0];   // [4096][128]
    const float* B   = (const float*)d_in[1];   // [128][64][128] = [8192][128]
    const float* var = (const float*)d_in[2];   // [1]
    float* out = (float*)d_out;                 // [4096][128]

    unsigned char* A8 = (unsigned char*)d_ws;            // 512 KB
    unsigned char* B8 = A8 + (size_t)NN * DD;            // 1 MB
    float* a2  = (float*)(B8 + (size_t)CC * DD);         // 16 KB
    float* b2  = a2 + NN;                                // 32 KB
    float* dpc = b2 + CC;                                // 2 MB, [MM][NN]

    prep_kernel<<<(NN + CC) / 8, 256, 0, stream>>>(A, B, A8, B8, a2, b2);
    kde_dens_kernel<<<2048, 256, 0, stream>>>(A8, B8, var, a2, b2, dpc);
    kde_norm_kernel<<<NN / 16, 256, 0, stream>>>(dpc, out);
}

// Round 12
// 82.003 us; speedup vs baseline: 1.0175x; 1.0175x over previous
//
#include <hip/hip_runtime.h>
#include <math.h>

// Problem constants (match reference setup_inputs)
#define NN 4096
#define MM 128
#define QQ 64
#define DD 128
#define CC (MM * QQ)          // 8192 gemm "columns" (flattened m,q)

typedef float f32x4 __attribute__((ext_vector_type(4)));
typedef int   i32x4 __attribute__((ext_vector_type(4)));
typedef int   i32x8 __attribute__((ext_vector_type(8)));

#define AS1 __attribute__((address_space(1)))
#define AS3 __attribute__((address_space(3)))

// ---- prep: fp32 -> fp8 e4m3 (OCP) convert + exact fp32 squared norms ----
// + zero den[] (read by norm; accumulated by dens via atomics)
__global__ __launch_bounds__(256)
void prep_kernel(const float* __restrict__ A, const float* __restrict__ B,
                 unsigned char* __restrict__ A8, unsigned char* __restrict__ B8,
                 float* __restrict__ a2, float* __restrict__ b2,
                 float* __restrict__ den)
{
    if (blockIdx.x < 16) den[blockIdx.x * 256 + threadIdx.x] = 0.f;   // 4096 floats

    const int row = blockIdx.x * 8 + (threadIdx.x >> 5);    // 0..12287
    const int l32 = threadIdx.x & 31;
    const float* src;
    unsigned char* dst;
    float* nrm;
    if (row < NN) { src = A + (size_t)row * DD; dst = A8 + (size_t)row * DD; nrm = a2 + row; }
    else {
        int r = row - NN;
        src = B + (size_t)r * DD; dst = B8 + (size_t)r * DD; nrm = b2 + r;
    }
    float4 v = ((const float4*)src)[l32];
    int pk = __builtin_amdgcn_cvt_pk_fp8_f32(v.x, v.y, 0, false);   // bytes 0,1
    pk     = __builtin_amdgcn_cvt_pk_fp8_f32(v.z, v.w, pk, true);   // bytes 2,3
    ((int*)dst)[l32] = pk;
    float s = v.x * v.x + v.y * v.y + v.z * v.z + v.w * v.w;
    #pragma unroll
    for (int m = 16; m > 0; m >>= 1) s += __shfl_xor(s, m, 64);  // stays in 32-group
    if (l32 == 0) *nrm = s;
}

// ---- dens: R9 structure (best, 76.8us) + critical-path micro-levers:
//  - var[0]/hinvL and all row norms loaded BEFORE the staging sync (their
//    latency hides under the global_load_lds drain; a2s/b2s LDS dropped)
//  - den[n] m-sum accumulated here via atomicAdd (norm's 128-add sum removed)
__global__ __launch_bounds__(256, 3)
void kde_dens_kernel(const unsigned char* __restrict__ A8,   // [NN][DD] fp8
                     const unsigned char* __restrict__ B8,   // [CC][DD] fp8
                     const float* __restrict__ var,
                     const float* __restrict__ a2w,          // [NN]
                     const float* __restrict__ b2w,          // [CC]
                     float* __restrict__ dpc,                // [MM][NN] transposed
                     float* __restrict__ den)                // [NN] m-sums
{
    __shared__ unsigned char As[128 * DD];   // 16 KB
    __shared__ unsigned char Bs[128 * DD];   // 16 KB

    // XCD swizzle: XCD x owns cb in [8x, 8x+8) -> B-tile L2 reuse within XCD
    const int lin = blockIdx.x;                 // 0..2047
    const int xcd = lin & 7;
    const int loc = lin >> 3;                   // 0..255
    const int cb  = (xcd << 3) | (loc & 7);     // 0..63
    const int nb  = loc >> 3;                   // 0..31
    const int n0  = nb * 128;
    const int c0  = cb * 128;

    const int t = threadIdx.x, w = t >> 6, lane = t & 63;
    const int l15 = lane & 15, q = lane >> 4, xr = l15 & 7;
    const int wy = w >> 1, wx = w & 1;
    const int rbase = wy * 64, cbase = wx * 64;
    const int m = (cb << 1) + wx;

    // hoisted scalars + norm loads: issued before the staging drain
    const float hinvL = (0.5f / var[0]) * 1.44269504088896f;  // 0.5/var * log2(e)
    const float h2L   = hinvL + hinvL;
    float a2r[4];
    #pragma unroll
    for (int i = 0; i < 4; ++i) a2r[i] = a2w[n0 + rbase + i * 16 + l15];
    f32x4 nbh[4];
    #pragma unroll
    for (int jc = 0; jc < 4; ++jc) {
        const f32x4 bv = *(const f32x4*)&b2w[c0 + cbase + jc * 16 + q * 4];
        nbh[jc] = -bv * hinvL;
    }

    // ---- async staging: 1024 A-chunks + 1024 B-chunks (16 B each) ----
    {
        const unsigned char* Ab = A8 + (size_t)n0 * DD;
        const unsigned char* Bb = B8 + (size_t)c0 * DD;
        #pragma unroll
        for (int i = 0; i < 4; ++i) {
            const int slot = w * 256 + i * 64 + lane;   // 0..1023
            const int r = slot >> 3, c16 = slot & 7, scb = c16 ^ (r & 7);
            __builtin_amdgcn_global_load_lds(
                (const AS1 unsigned int*)(Ab + r * DD + scb * 16),
                (AS3 unsigned int*)&As[slot * 16], 16, 0, 0);
            __builtin_amdgcn_global_load_lds(
                (const AS1 unsigned int*)(Bb + r * DD + scb * 16),
                (AS3 unsigned int*)&Bs[slot * 16], 16, 0, 0);
        }
    }
    __syncthreads();   // drains vmcnt(0) incl. global_load_lds + norm loads

    // B-fragments (loaded once)
    i32x8 b8v[4];
    #pragma unroll
    for (int jc = 0; jc < 4; ++jc) {
        const int ro = (cbase + jc * 16 + l15) * DD;
        const i32x4 lo = *(const i32x4*)&Bs[ro + (((q << 1) | 0) ^ xr) * 16];
        const i32x4 hi = *(const i32x4*)&Bs[ro + (((q << 1) | 1) ^ xr) * 16];
        #pragma unroll
        for (int e = 0; e < 4; ++e) { b8v[jc][e] = lo[e]; b8v[jc][4 + e] = hi[e]; }
    }

    // A fragments: lane holds A[rbase+i*16+l15][q*32 .. q*32+31]
    i32x8 a8[4];
    #pragma unroll
    for (int i = 0; i < 4; ++i) {
        const int ro = (rbase + i * 16 + l15) * DD;
        const i32x4 lo = *(const i32x4*)&As[ro + (((q << 1) | 0) ^ xr) * 16];
        const i32x4 hi = *(const i32x4*)&As[ro + (((q << 1) | 1) ^ xr) * 16];
        #pragma unroll
        for (int e = 0; e < 4; ++e) { a8[i][e] = lo[e]; a8[i][4 + e] = hi[e]; }
    }

    // Swapped operands -> c-reduction in-register. 16 independent MFMAs.
    f32x4 acc[4][4] = {};
    __builtin_amdgcn_s_setprio(1);
    #pragma unroll
    for (int jc = 0; jc < 4; ++jc)
        #pragma unroll
        for (int i = 0; i < 4; ++i)
            acc[jc][i] = __builtin_amdgcn_mfma_scale_f32_16x16x128_f8f6f4(
                            b8v[jc], a8[i], acc[jc][i],
                            0, 0,          // cbsz=0 (fp8), blgp=0 (fp8)
                            0, 127,        // scale_a = 1.0
                            0, 127);       // scale_b = 1.0
    __builtin_amdgcn_s_setprio(0);

    // epilogue: dens = exp2(log2e*(2ab - a2 - b2)*0.5/var);
    // 16 c lane-local -> 2 partial chains + 4-way over q (2 shfl_xor).
    float sums[4];
    #pragma unroll
    for (int i = 0; i < 4; ++i) {
        const float aih = a2r[i] * hinvL;
        float s0 = 0.f, s1 = 0.f;
        #pragma unroll
        for (int jc = 0; jc < 4; jc += 2) {
            #pragma unroll
            for (int r = 0; r < 4; ++r) {
                s0 += __builtin_amdgcn_exp2f(fmaf(h2L, acc[jc][i][r],     nbh[jc][r]     - aih));
                s1 += __builtin_amdgcn_exp2f(fmaf(h2L, acc[jc + 1][i][r], nbh[jc + 1][r] - aih));
            }
        }
        float s = s0 + s1;
        s += __shfl_xor(s, 16, 64);
        s += __shfl_xor(s, 32, 64);
        sums[i] = s;   // full 64-col sum for n = rbase + i*16 + l15
    }
    // lane owns n = rbase + lane (i == q); static select; coalesced store
    const float v01 = (q & 1) ? sums[1] : sums[0];
    const float v23 = (q & 1) ? sums[3] : sums[2];
    const float myv = (q & 2) ? v23 : v01;
    dpc[(size_t)m * NN + n0 + rbase + lane] = myv;
    atomicAdd(&den[n0 + rbase + lane], myv);   // m-sum for norm (order-free)
}

// ---- normalize: out[n,m] = dpc[m,n] * 1/(den[n] + 1e-10) ----
// (sum precomputed by dens; this is now a pure LDS transpose + scale)
__global__ __launch_bounds__(256)
void kde_norm_kernel(const float* __restrict__ dpc, const float* __restrict__ den,
                     float* __restrict__ out)
{
    __shared__ float tile[128][17];    // [m][nloc], odd stride
    __shared__ float rden[16];
    const int n0 = blockIdx.x * 16;
    const int t  = threadIdx.x;

    if (t < 16) rden[t] = 1.f / (den[n0 + t] + 1e-10f);

    const int mr = t >> 1, half = t & 1;   // 128 rows x 2 threads
    {
        const float4 va = *(const float4*)&dpc[(size_t)mr * NN + n0 + half * 8];
        const float4 vb = *(const float4*)&dpc[(size_t)mr * NN + n0 + half * 8 + 4];
        float* tr = &tile[mr][half * 8];
        tr[0] = va.x; tr[1] = va.y; tr[2] = va.z; tr[3] = va.w;
        tr[4] = vb.x; tr[5] = vb.y; tr[6] = vb.z; tr[7] = vb.w;
    }
    __syncthreads();

    const int j = t >> 4, m0 = (t & 15) * 8;
    const float r = rden[j];
    float4 o0, o1;
    o0.x = tile[m0][j] * r;     o0.y = tile[m0 + 1][j] * r;
    o0.z = tile[m0 + 2][j] * r; o0.w = tile[m0 + 3][j] * r;
    o1.x = tile[m0 + 4][j] * r; o1.y = tile[m0 + 5][j] * r;
    o1.z = tile[m0 + 6][j] * r; o1.w = tile[m0 + 7][j] * r;
    float* obase = &out[(size_t)(n0 + j) * MM + m0];
    *(float4*)obase       = o0;
    *(float4*)(obase + 4) = o1;   // 512B per 16-thread group, coalesced
}

extern "C" void kernel_launch(void* const* d_in, const int* in_sizes, int n_in,
                              void* d_out, int out_size, void* d_ws, size_t ws_size,
                              hipStream_t stream) {
    const float* A   = (const float*)d_in[0];   // [4096][128]
    const float* B   = (const float*)d_in[1];   // [128][64][128] = [8192][128]
    const float* var = (const float*)d_in[2];   // [1]
    float* out = (float*)d_out;                 // [4096][128]

    unsigned char* A8 = (unsigned char*)d_ws;            // 512 KB
    unsigned char* B8 = A8 + (size_t)NN * DD;            // 1 MB
    float* a2  = (float*)(B8 + (size_t)CC * DD);         // 16 KB
    float* b2  = a2 + NN;                                // 32 KB
    float* den = b2 + CC;                                // 16 KB, [NN]
    float* dpc = den + NN;                               // 2 MB, [MM][NN]

    prep_kernel<<<(NN + CC) / 8, 256, 0, stream>>>(A, B, A8, B8, a2, b2, den);
    kde_dens_kernel<<<2048, 256, 0, stream>>>(A8, B8, var, a2, b2, dpc, den);
    kde_norm_kernel<<<NN / 16, 256, 0, stream>>>(dpc, den, out);
}

// Round 13
// 76.829 us; speedup vs baseline: 1.0860x; 1.0673x over previous
//
#include <hip/hip_runtime.h>
#include <math.h>

// Problem constants (match reference setup_inputs)
#define NN 4096
#define MM 128
#define QQ 64
#define DD 128
#define CC (MM * QQ)          // 8192 gemm "columns" (flattened m,q)

typedef float f32x4 __attribute__((ext_vector_type(4)));
typedef int   i32x4 __attribute__((ext_vector_type(4)));
typedef int   i32x8 __attribute__((ext_vector_type(8)));

#define AS1 __attribute__((address_space(1)))
#define AS3 __attribute__((address_space(3)))

// ---- prep: fp32 -> fp8 e4m3 (OCP) convert + exact fp32 squared norms ----
// (plain stores; cross-kernel visibility from the dispatch boundary)
__global__ __launch_bounds__(256)
void prep_kernel(const float* __restrict__ A, const float* __restrict__ B,
                 unsigned char* __restrict__ A8, unsigned char* __restrict__ B8,
                 float* __restrict__ a2, float* __restrict__ b2)
{
    const int row = blockIdx.x * 8 + (threadIdx.x >> 5);    // 0..12287
    const int l32 = threadIdx.x & 31;
    const float* src;
    unsigned char* dst;
    float* nrm;
    if (row < NN) { src = A + (size_t)row * DD; dst = A8 + (size_t)row * DD; nrm = a2 + row; }
    else {
        int r = row - NN;
        src = B + (size_t)r * DD; dst = B8 + (size_t)r * DD; nrm = b2 + r;
    }
    float4 v = ((const float4*)src)[l32];
    int pk = __builtin_amdgcn_cvt_pk_fp8_f32(v.x, v.y, 0, false);   // bytes 0,1
    pk     = __builtin_amdgcn_cvt_pk_fp8_f32(v.z, v.w, pk, true);   // bytes 2,3
    ((int*)dst)[l32] = pk;
    float s = v.x * v.x + v.y * v.y + v.z * v.z + v.w * v.w;
    #pragma unroll
    for (int m = 16; m > 0; m >>= 1) s += __shfl_xor(s, m, 64);  // stays in 32-group
    if (l32 == 0) *nrm = s;
}

// ---- dens: one 128n x 128c tile per block, 2048 independently-scheduled
// blocks. Session-verified best structure (R9, 76.8us). Swapped-operand MFMA:
// D[row=c][col=n] puts the c-reduction in-register (15 adds + 2 shfl_xor,
// no LDS round-trip). XOR chunk swizzle on staging; XCD swizzle for B-tile
// L2 reuse. Falsified alternatives (do NOT revisit): persistent-fused grid
// (R5-8: phase-locked waves, barrier cost), zero-LDS gather (R11: 8x L2
// request amplification), per-n atomicAdd den (R12: 128-way contention),
// producer-fused conversion (R4: 64x redundant work), 512-thread blocks
// (R8: more identically-phased waves, no overlap gain).
__global__ __launch_bounds__(256, 3)
void kde_dens_kernel(const unsigned char* __restrict__ A8,   // [NN][DD] fp8
                     const unsigned char* __restrict__ B8,   // [CC][DD] fp8
                     const float* __restrict__ var,
                     const float* __restrict__ a2w,          // [NN]
                     const float* __restrict__ b2w,          // [CC]
                     float* __restrict__ dpc)                // [MM][NN] transposed
{
    __shared__ unsigned char As[128 * DD];   // 16 KB
    __shared__ unsigned char Bs[128 * DD];   // 16 KB
    __shared__ float a2s[128];
    __shared__ float b2s[128];

    // XCD swizzle: XCD x owns cb in [8x, 8x+8) -> B-tile L2 reuse within XCD
    const int lin = blockIdx.x;                 // 0..2047
    const int xcd = lin & 7;
    const int loc = lin >> 3;                   // 0..255
    const int cb  = (xcd << 3) | (loc & 7);     // 0..63
    const int nb  = loc >> 3;                   // 0..31
    const int n0  = nb * 128;
    const int c0  = cb * 128;

    const int t = threadIdx.x, w = t >> 6, lane = t & 63;

    // ---- async staging: 1024 A-chunks + 1024 B-chunks (16 B each) ----
    {
        const unsigned char* Ab = A8 + (size_t)n0 * DD;
        const unsigned char* Bb = B8 + (size_t)c0 * DD;
        #pragma unroll
        for (int i = 0; i < 4; ++i) {
            const int slot = w * 256 + i * 64 + lane;   // 0..1023
            const int r = slot >> 3, c16 = slot & 7, scb = c16 ^ (r & 7);
            __builtin_amdgcn_global_load_lds(
                (const AS1 unsigned int*)(Ab + r * DD + scb * 16),
                (AS3 unsigned int*)&As[slot * 16], 16, 0, 0);
            __builtin_amdgcn_global_load_lds(
                (const AS1 unsigned int*)(Bb + r * DD + scb * 16),
                (AS3 unsigned int*)&Bs[slot * 16], 16, 0, 0);
        }
        if (t < 128)        a2s[t]       = a2w[n0 + t];
        else                b2s[t - 128] = b2w[c0 + (t - 128)];
    }
    __syncthreads();   // drains vmcnt(0) incl. global_load_lds

    // ---- wave (wy,wx): rows wy*64+[0,64), cols wx*64+[0,64) (one m) ----
    const int l15 = lane & 15, q = lane >> 4, xr = l15 & 7;
    const int wy = w >> 1, wx = w & 1;
    const int rbase = wy * 64, cbase = wx * 64;
    const int m = (cb << 1) + wx;
    const float hinvL = (0.5f / var[0]) * 1.44269504088896f;  // 0.5/var * log2(e)
    const float h2L   = hinvL + hinvL;

    // c-side factors + B-fragments (loaded once)
    f32x4 nbh[4];
    i32x8 b8v[4];
    #pragma unroll
    for (int jc = 0; jc < 4; ++jc) {
        const f32x4 bv = *(const f32x4*)&b2s[cbase + jc * 16 + q * 4];
        nbh[jc] = -bv * hinvL;
        const int ro = (cbase + jc * 16 + l15) * DD;
        const i32x4 lo = *(const i32x4*)&Bs[ro + (((q << 1) | 0) ^ xr) * 16];
        const i32x4 hi = *(const i32x4*)&Bs[ro + (((q << 1) | 1) ^ xr) * 16];
        #pragma unroll
        for (int e = 0; e < 4; ++e) { b8v[jc][e] = lo[e]; b8v[jc][4 + e] = hi[e]; }
    }

    // A fragments: lane holds A[rbase+i*16+l15][q*32 .. q*32+31]
    i32x8 a8[4];
    #pragma unroll
    for (int i = 0; i < 4; ++i) {
        const int ro = (rbase + i * 16 + l15) * DD;
        const i32x4 lo = *(const i32x4*)&As[ro + (((q << 1) | 0) ^ xr) * 16];
        const i32x4 hi = *(const i32x4*)&As[ro + (((q << 1) | 1) ^ xr) * 16];
        #pragma unroll
        for (int e = 0; e < 4; ++e) { a8[i][e] = lo[e]; a8[i][4 + e] = hi[e]; }
    }

    // Swapped operands -> c-reduction in-register. 16 MFMAs, pure-register.
    f32x4 acc[4][4] = {};
    __builtin_amdgcn_s_setprio(1);
    #pragma unroll
    for (int jc = 0; jc < 4; ++jc)
        #pragma unroll
        for (int i = 0; i < 4; ++i)
            acc[jc][i] = __builtin_amdgcn_mfma_scale_f32_16x16x128_f8f6f4(
                            b8v[jc], a8[i], acc[jc][i],
                            0, 0,          // cbsz=0 (fp8), blgp=0 (fp8)
                            0, 127,        // scale_a = 1.0
                            0, 127);       // scale_b = 1.0
    __builtin_amdgcn_s_setprio(0);

    // epilogue: dens = exp2(log2e*(2ab - a2 - b2)*0.5/var);
    // 16 c lane-local -> 2 partial chains + 4-way over q (2 shfl_xor).
    float sums[4];
    #pragma unroll
    for (int i = 0; i < 4; ++i) {
        const float aih = a2s[rbase + i * 16 + l15] * hinvL;
        float s0 = 0.f, s1 = 0.f;
        #pragma unroll
        for (int jc = 0; jc < 4; jc += 2) {
            #pragma unroll
            for (int r = 0; r < 4; ++r) {
                s0 += __builtin_amdgcn_exp2f(fmaf(h2L, acc[jc][i][r],     nbh[jc][r]     - aih));
                s1 += __builtin_amdgcn_exp2f(fmaf(h2L, acc[jc + 1][i][r], nbh[jc + 1][r] - aih));
            }
        }
        float s = s0 + s1;
        s += __shfl_xor(s, 16, 64);
        s += __shfl_xor(s, 32, 64);
        sums[i] = s;   // full 64-col sum for n = rbase + i*16 + l15
    }
    // lane owns n = rbase + lane (i == q); static select; coalesced store
    const float v01 = (q & 1) ? sums[1] : sums[0];
    const float v23 = (q & 1) ? sums[3] : sums[2];
    const float myv = (q & 2) ? v23 : v01;
    dpc[(size_t)m * NN + n0 + rbase + lane] = myv;
}

// ---- normalize: out[n,m] = dpc[m,n] / (sum_m dpc[:,n] + 1e-10) ----
// 256 blocks x 16 n each; m-ascending sum order matches reference.
__global__ __launch_bounds__(256)
void kde_norm_kernel(const float* __restrict__ dpc, float* __restrict__ out)
{
    __shared__ float tile[128][17];    // [m][nloc], odd stride
    __shared__ float rden[16];
    const int n0 = blockIdx.x * 16;
    const int t  = threadIdx.x;

    const int mr = t >> 1, half = t & 1;   // 128 rows x 2 threads
    {
        const float4 va = *(const float4*)&dpc[(size_t)mr * NN + n0 + half * 8];
        const float4 vb = *(const float4*)&dpc[(size_t)mr * NN + n0 + half * 8 + 4];
        float* tr = &tile[mr][half * 8];
        tr[0] = va.x; tr[1] = va.y; tr[2] = va.z; tr[3] = va.w;
        tr[4] = vb.x; tr[5] = vb.y; tr[6] = vb.z; tr[7] = vb.w;
    }
    __syncthreads();

    if (t < 16) {
        float s = 0.f;
        #pragma unroll 8
        for (int mm = 0; mm < MM; ++mm) s += tile[mm][t];   // m ascending, matches ref
        rden[t] = 1.f / (s + 1e-10f);
    }
    __syncthreads();

    const int j = t >> 4, m0 = (t & 15) * 8;
    const float r = rden[j];
    float4 o0, o1;
    o0.x = tile[m0][j] * r;     o0.y = tile[m0 + 1][j] * r;
    o0.z = tile[m0 + 2][j] * r; o0.w = tile[m0 + 3][j] * r;
    o1.x = tile[m0 + 4][j] * r; o1.y = tile[m0 + 5][j] * r;
    o1.z = tile[m0 + 6][j] * r; o1.w = tile[m0 + 7][j] * r;
    float* obase = &out[(size_t)(n0 + j) * MM + m0];
    *(float4*)obase       = o0;
    *(float4*)(obase + 4) = o1;   // 512B per 16-thread group, coalesced
}

extern "C" void kernel_launch(void* const* d_in, const int* in_sizes, int n_in,
                              void* d_out, int out_size, void* d_ws, size_t ws_size,
                              hipStream_t stream) {
    const float* A   = (const float*)d_in[0];   // [4096][128]
    const float* B   = (const float*)d_in[1];   // [128][64][128] = [8192][128]
    const float* var = (const float*)d_in[2];   // [1]
    float* out = (float*)d_out;                 // [4096][128]

    unsigned char* A8 = (unsigned char*)d_ws;            // 512 KB
    unsigned char* B8 = A8 + (size_t)NN * DD;            // 1 MB
    float* a2  = (float*)(B8 + (size_t)CC * DD);         // 16 KB
    float* b2  = a2 + NN;                                // 32 KB
    float* dpc = b2 + CC;                                // 2 MB, [MM][NN]

    prep_kernel<<<(NN + CC) / 8, 256, 0, stream>>>(A, B, A8, B8, a2, b2);
    kde_dens_kernel<<<2048, 256, 0, stream>>>(A8, B8, var, a2, b2, dpc);
    kde_norm_kernel<<<NN / 16, 256, 0, stream>>>(dpc, out);
}

// Round 15
// 73.965 us; speedup vs baseline: 1.1280x; 1.0387x over previous
//
#include <hip/hip_runtime.h>
#include <math.h>

// Problem constants (match reference setup_inputs)
#define NN 4096
#define MM 128
#define QQ 64
#define DD 128
#define CC (MM * QQ)          // 8192 gemm "columns" (flattened m,q)

typedef float f32x4 __attribute__((ext_vector_type(4)));
typedef int   i32x4 __attribute__((ext_vector_type(4)));
typedef int   i32x8 __attribute__((ext_vector_type(8)));

#define AS1 __attribute__((address_space(1)))
#define AS3 __attribute__((address_space(3)))

// ---- prep: fp32 -> fp8 e4m3 (OCP) convert + exact fp32 squared norms ----
__global__ __launch_bounds__(256)
void prep_kernel(const float* __restrict__ A, const float* __restrict__ B,
                 unsigned char* __restrict__ A8, unsigned char* __restrict__ B8,
                 float* __restrict__ a2, float* __restrict__ b2)
{
    const int row = blockIdx.x * 8 + (threadIdx.x >> 5);    // 0..12287
    const int l32 = threadIdx.x & 31;
    const float* src;
    unsigned char* dst;
    float* nrm;
    if (row < NN) { src = A + (size_t)row * DD; dst = A8 + (size_t)row * DD; nrm = a2 + row; }
    else {
        int r = row - NN;
        src = B + (size_t)r * DD; dst = B8 + (size_t)r * DD; nrm = b2 + r;
    }
    float4 v = ((const float4*)src)[l32];
    int pk = __builtin_amdgcn_cvt_pk_fp8_f32(v.x, v.y, 0, false);   // bytes 0,1
    pk     = __builtin_amdgcn_cvt_pk_fp8_f32(v.z, v.w, pk, true);   // bytes 2,3
    ((int*)dst)[l32] = pk;
    float s = v.x * v.x + v.y * v.y + v.z * v.z + v.w * v.w;
    #pragma unroll
    for (int m = 16; m > 0; m >>= 1) s += __shfl_xor(s, m, 64);  // stays in 32-group
    if (l32 == 0) *nrm = s;
}

// ---- dens: R9/R13 structure (verified best, 76.8us reproducible) + R14's
// underflow tile-skip: per wave, an upper bound on the largest exp2 arg is
// computed from 15 acc-maxes + the hoisted c-side max; if no lane's bound
// exceeds -126 the whole 64-exp block is exactly 0 in fp32 (skipped terms
// < 2^-126 each, <= 7.6e-37 summed -- exact for this tolerance on ANY input,
// and on this data distribution every tile underflows). This removes ~75% of
// the epilogue VALU work; it is also the last untested mechanism class
// (compute volume -- all falsified experiments were memory/sync structure).
__global__ __launch_bounds__(256, 3)
void kde_dens_kernel(const unsigned char* __restrict__ A8,   // [NN][DD] fp8
                     const unsigned char* __restrict__ B8,   // [CC][DD] fp8
                     const float* __restrict__ var,
                     const float* __restrict__ a2w,          // [NN]
                     const float* __restrict__ b2w,          // [CC]
                     float* __restrict__ dpc)                // [MM][NN] transposed
{
    __shared__ unsigned char As[128 * DD];   // 16 KB
    __shared__ unsigned char Bs[128 * DD];   // 16 KB
    __shared__ float a2s[128];
    __shared__ float b2s[128];

    // XCD swizzle: XCD x owns cb in [8x, 8x+8) -> B-tile L2 reuse within XCD
    const int lin = blockIdx.x;                 // 0..2047
    const int xcd = lin & 7;
    const int loc = lin >> 3;                   // 0..255
    const int cb  = (xcd << 3) | (loc & 7);     // 0..63
    const int nb  = loc >> 3;                   // 0..31
    const int n0  = nb * 128;
    const int c0  = cb * 128;

    const int t = threadIdx.x, w = t >> 6, lane = t & 63;

    // ---- async staging: 1024 A-chunks + 1024 B-chunks (16 B each) ----
    {
        const unsigned char* Ab = A8 + (size_t)n0 * DD;
        const unsigned char* Bb = B8 + (size_t)c0 * DD;
        #pragma unroll
        for (int i = 0; i < 4; ++i) {
            const int slot = w * 256 + i * 64 + lane;   // 0..1023
            const int r = slot >> 3, c16 = slot & 7, scb = c16 ^ (r & 7);
            __builtin_amdgcn_global_load_lds(
                (const AS1 unsigned int*)(Ab + r * DD + scb * 16),
                (AS3 unsigned int*)&As[slot * 16], 16, 0, 0);
            __builtin_amdgcn_global_load_lds(
                (const AS1 unsigned int*)(Bb + r * DD + scb * 16),
                (AS3 unsigned int*)&Bs[slot * 16], 16, 0, 0);
        }
        if (t < 128)        a2s[t]       = a2w[n0 + t];
        else                b2s[t - 128] = b2w[c0 + (t - 128)];
    }
    __syncthreads();   // drains vmcnt(0) incl. global_load_lds

    // ---- wave (wy,wx): rows wy*64+[0,64), cols wx*64+[0,64) (one m) ----
    const int l15 = lane & 15, q = lane >> 4, xr = l15 & 7;
    const int wy = w >> 1, wx = w & 1;
    const int rbase = wy * 64, cbase = wx * 64;
    const int m = (cb << 1) + wx;
    const float hinvL = (0.5f / var[0]) * 1.44269504088896f;  // 0.5/var * log2(e)
    const float h2L   = hinvL + hinvL;

    // c-side factors + B-fragments (loaded once)
    f32x4 nbh[4];
    i32x8 b8v[4];
    #pragma unroll
    for (int jc = 0; jc < 4; ++jc) {
        const f32x4 bv = *(const f32x4*)&b2s[cbase + jc * 16 + q * 4];
        nbh[jc] = -bv * hinvL;
        const int ro = (cbase + jc * 16 + l15) * DD;
        const i32x4 lo = *(const i32x4*)&Bs[ro + (((q << 1) | 0) ^ xr) * 16];
        const i32x4 hi = *(const i32x4*)&Bs[ro + (((q << 1) | 1) ^ xr) * 16];
        #pragma unroll
        for (int e = 0; e < 4; ++e) { b8v[jc][e] = lo[e]; b8v[jc][4 + e] = hi[e]; }
    }
    // hoisted per-thread max of the c-side term (for the underflow bound)
    float nbmax = nbh[0][0];
    #pragma unroll
    for (int jc = 0; jc < 4; ++jc)
        #pragma unroll
        for (int r = 0; r < 4; ++r) nbmax = fmaxf(nbmax, nbh[jc][r]);

    // A fragments: lane holds A[rbase+i*16+l15][q*32 .. q*32+31]
    i32x8 a8[4];
    #pragma unroll
    for (int i = 0; i < 4; ++i) {
        const int ro = (rbase + i * 16 + l15) * DD;
        const i32x4 lo = *(const i32x4*)&As[ro + (((q << 1) | 0) ^ xr) * 16];
        const i32x4 hi = *(const i32x4*)&As[ro + (((q << 1) | 1) ^ xr) * 16];
        #pragma unroll
        for (int e = 0; e < 4; ++e) { a8[i][e] = lo[e]; a8[i][4 + e] = hi[e]; }
    }

    // Swapped operands -> c-reduction in-register. 16 MFMAs, pure-register.
    f32x4 acc[4][4] = {};
    __builtin_amdgcn_s_setprio(1);
    #pragma unroll
    for (int jc = 0; jc < 4; ++jc)
        #pragma unroll
        for (int i = 0; i < 4; ++i)
            acc[jc][i] = __builtin_amdgcn_mfma_scale_f32_16x16x128_f8f6f4(
                            b8v[jc], a8[i], acc[jc][i],
                            0, 0,          // cbsz=0 (fp8), blgp=0 (fp8)
                            0, 127,        // scale_a = 1.0
                            0, 127);       // scale_b = 1.0
    __builtin_amdgcn_s_setprio(0);

    // epilogue: dens = exp2(log2e*(2ab - a2 - b2)*0.5/var);
    // 16 c lane-local -> 2 partial chains + 4-way over q (2 shfl_xor).
    // Underflow tile-skip: arg = h2L*acc + nbh - aih <= h2L*mx + nbmax - aih;
    // if no lane in the wave exceeds -126, every exp2 is exactly 0.0f.
    float sums[4];
    #pragma unroll
    for (int i = 0; i < 4; ++i) {
        const float aih = a2s[rbase + i * 16 + l15] * hinvL;
        float mx = acc[0][i][0];
        #pragma unroll
        for (int jc = 0; jc < 4; ++jc)
            #pragma unroll
            for (int r = 0; r < 4; ++r) mx = fmaxf(mx, acc[jc][i][r]);
        float s;
        if (__any(fmaf(h2L, mx, nbmax - aih) > -126.f)) {
            float s0 = 0.f, s1 = 0.f;
            #pragma unroll
            for (int jc = 0; jc < 4; jc += 2) {
                #pragma unroll
                for (int r = 0; r < 4; ++r) {
                    s0 += __builtin_amdgcn_exp2f(fmaf(h2L, acc[jc][i][r],     nbh[jc][r]     - aih));
                    s1 += __builtin_amdgcn_exp2f(fmaf(h2L, acc[jc + 1][i][r], nbh[jc + 1][r] - aih));
                }
            }
            s = s0 + s1;
        } else {
            s = 0.f;   // exact: all 16 exp2 underflow to +0.0f
        }
        s += __shfl_xor(s, 16, 64);
        s += __shfl_xor(s, 32, 64);
        sums[i] = s;   // full 64-col sum for n = rbase + i*16 + l15
    }
    // lane owns n = rbase + lane (i == q); static select; coalesced store
    const float v01 = (q & 1) ? sums[1] : sums[0];
    const float v23 = (q & 1) ? sums[3] : sums[2];
    const float myv = (q & 2) ? v23 : v01;
    dpc[(size_t)m * NN + n0 + rbase + lane] = myv;
}

// ---- normalize: out[n,m] = dpc[m,n] / (sum_m dpc[:,n] + 1e-10) ----
// 256 blocks x 16 n each; m-ascending sum order matches reference.
__global__ __launch_bounds__(256)
void kde_norm_kernel(const float* __restrict__ dpc, float* __restrict__ out)
{
    __shared__ float tile[128][17];    // [m][nloc], odd stride
    __shared__ float rden[16];
    const int n0 = blockIdx.x * 16;
    const int t  = threadIdx.x;

    const int mr = t >> 1, half = t & 1;   // 128 rows x 2 threads
    {
        const float4 va = *(const float4*)&dpc[(size_t)mr * NN + n0 + half * 8];
        const float4 vb = *(const float4*)&dpc[(size_t)mr * NN + n0 + half * 8 + 4];
        float* tr = &tile[mr][half * 8];
        tr[0] = va.x; tr[1] = va.y; tr[2] = va.z; tr[3] = va.w;
        tr[4] = vb.x; tr[5] = vb.y; tr[6] = vb.z; tr[7] = vb.w;
    }
    __syncthreads();

    if (t < 16) {
        float s = 0.f;
        #pragma unroll 8
        for (int mm = 0; mm < MM; ++mm) s += tile[mm][t];   // m ascending, matches ref
        rden[t] = 1.f / (s + 1e-10f);
    }
    __syncthreads();

    const int j = t >> 4, m0 = (t & 15) * 8;
    const float r = rden[j];
    float4 o0, o1;
    o0.x = tile[m0][j] * r;     o0.y = tile[m0 + 1][j] * r;
    o0.z = tile[m0 + 2][j] * r; o0.w = tile[m0 + 3][j] * r;
    o1.x = tile[m0 + 4][j] * r; o1.y = tile[m0 + 5][j] * r;
    o1.z = tile[m0 + 6][j] * r; o1.w = tile[m0 + 7][j] * r;
    float* obase = &out[(size_t)(n0 + j) * MM + m0];
    *(float4*)obase       = o0;
    *(float4*)(obase + 4) = o1;   // 512B per 16-thread group, coalesced
}

extern "C" void kernel_launch(void* const* d_in, const int* in_sizes, int n_in,
                              void* d_out, int out_size, void* d_ws, size_t ws_size,
                              hipStream_t stream) {
    const float* A   = (const float*)d_in[0];   // [4096][128]
    const float* B   = (const float*)d_in[1];   // [128][64][128] = [8192][128]
    const float* var = (const float*)d_in[2];   // [1]
    float* out = (float*)d_out;                 // [4096][128]

    unsigned char* A8 = (unsigned char*)d_ws;            // 512 KB
    unsigned char* B8 = A8 + (size_t)NN * DD;            // 1 MB
    float* a2  = (float*)(B8 + (size_t)CC * DD);         // 16 KB
    float* b2  = a2 + NN;                                // 32 KB
    float* dpc = b2 + CC;                                // 2 MB, [MM][NN]

    prep_kernel<<<(NN + CC) / 8, 256, 0, stream>>>(A, B, A8, B8, a2, b2);
    kde_dens_kernel<<<2048, 256, 0, stream>>>(A8, B8, var, a2, b2, dpc);
    kde_norm_kernel<<<NN / 16, 256, 0, stream>>>(dpc, out);
}

// Round 16
// 73.900 us; speedup vs baseline: 1.1290x; 1.0009x over previous
//
#include <hip/hip_runtime.h>
#include <math.h>

// Problem constants (match reference setup_inputs)
#define NN 4096
#define MM 128
#define QQ 64
#define DD 128
#define CC (MM * QQ)          // 8192 gemm "columns" (flattened m,q)

typedef float f32x4 __attribute__((ext_vector_type(4)));
typedef int   i32x4 __attribute__((ext_vector_type(4)));
typedef int   i32x8 __attribute__((ext_vector_type(8)));

#define AS1 __attribute__((address_space(1)))
#define AS3 __attribute__((address_space(3)))

// ---- prep: fp32 -> fp8 e4m3 (OCP) convert + exact fp32 squared norms ----
__global__ __launch_bounds__(256)
void prep_kernel(const float* __restrict__ A, const float* __restrict__ B,
                 unsigned char* __restrict__ A8, unsigned char* __restrict__ B8,
                 float* __restrict__ a2, float* __restrict__ b2)
{
    const int row = blockIdx.x * 8 + (threadIdx.x >> 5);    // 0..12287
    const int l32 = threadIdx.x & 31;
    const float* src;
    unsigned char* dst;
    float* nrm;
    if (row < NN) { src = A + (size_t)row * DD; dst = A8 + (size_t)row * DD; nrm = a2 + row; }
    else {
        int r = row - NN;
        src = B + (size_t)r * DD; dst = B8 + (size_t)r * DD; nrm = b2 + r;
    }
    float4 v = ((const float4*)src)[l32];
    int pk = __builtin_amdgcn_cvt_pk_fp8_f32(v.x, v.y, 0, false);   // bytes 0,1
    pk     = __builtin_amdgcn_cvt_pk_fp8_f32(v.z, v.w, pk, true);   // bytes 2,3
    ((int*)dst)[l32] = pk;
    float s = v.x * v.x + v.y * v.y + v.z * v.z + v.w * v.w;
    #pragma unroll
    for (int m = 16; m > 0; m >>= 1) s += __shfl_xor(s, m, 64);  // stays in 32-group
    if (l32 == 0) *nrm = s;
}

// ---- dens: R9/R13 structure + R15's verified underflow tile-skip (exact:
// skipped terms < 2^-126 each), tightened in R16:
//  - ONE wave-level bound (h2L*max(all acc) + nbmax - min_i aih >= all per-i
//    bounds) -> 1 ballot instead of 4
//  - max via nested fmaxf triples -> v_max3_f32 (T17), log-depth tree
//  - skip path stores 0 directly: no shfl_xor, no sums[], no selects
// Non-skip path is byte-identical to the verified R15 epilogue.
__global__ __launch_bounds__(256, 3)
void kde_dens_kernel(const unsigned char* __restrict__ A8,   // [NN][DD] fp8
                     const unsigned char* __restrict__ B8,   // [CC][DD] fp8
                     const float* __restrict__ var,
                     const float* __restrict__ a2w,          // [NN]
                     const float* __restrict__ b2w,          // [CC]
                     float* __restrict__ dpc)                // [MM][NN] transposed
{
    __shared__ unsigned char As[128 * DD];   // 16 KB
    __shared__ unsigned char Bs[128 * DD];   // 16 KB
    __shared__ float a2s[128];
    __shared__ float b2s[128];

    // XCD swizzle: XCD x owns cb in [8x, 8x+8) -> B-tile L2 reuse within XCD
    const int lin = blockIdx.x;                 // 0..2047
    const int xcd = lin & 7;
    const int loc = lin >> 3;                   // 0..255
    const int cb  = (xcd << 3) | (loc & 7);     // 0..63
    const int nb  = loc >> 3;                   // 0..31
    const int n0  = nb * 128;
    const int c0  = cb * 128;

    const int t = threadIdx.x, w = t >> 6, lane = t & 63;

    // ---- async staging: 1024 A-chunks + 1024 B-chunks (16 B each) ----
    {
        const unsigned char* Ab = A8 + (size_t)n0 * DD;
        const unsigned char* Bb = B8 + (size_t)c0 * DD;
        #pragma unroll
        for (int i = 0; i < 4; ++i) {
            const int slot = w * 256 + i * 64 + lane;   // 0..1023
            const int r = slot >> 3, c16 = slot & 7, scb = c16 ^ (r & 7);
            __builtin_amdgcn_global_load_lds(
                (const AS1 unsigned int*)(Ab + r * DD + scb * 16),
                (AS3 unsigned int*)&As[slot * 16], 16, 0, 0);
            __builtin_amdgcn_global_load_lds(
                (const AS1 unsigned int*)(Bb + r * DD + scb * 16),
                (AS3 unsigned int*)&Bs[slot * 16], 16, 0, 0);
        }
        if (t < 128)        a2s[t]       = a2w[n0 + t];
        else                b2s[t - 128] = b2w[c0 + (t - 128)];
    }
    __syncthreads();   // drains vmcnt(0) incl. global_load_lds

    // ---- wave (wy,wx): rows wy*64+[0,64), cols wx*64+[0,64) (one m) ----
    const int l15 = lane & 15, q = lane >> 4, xr = l15 & 7;
    const int wy = w >> 1, wx = w & 1;
    const int rbase = wy * 64, cbase = wx * 64;
    const int m = (cb << 1) + wx;
    const float hinvL = (0.5f / var[0]) * 1.44269504088896f;  // 0.5/var * log2(e)
    const float h2L   = hinvL + hinvL;

    // c-side factors + B-fragments (loaded once)
    f32x4 nbh[4];
    i32x8 b8v[4];
    #pragma unroll
    for (int jc = 0; jc < 4; ++jc) {
        const f32x4 bv = *(const f32x4*)&b2s[cbase + jc * 16 + q * 4];
        nbh[jc] = -bv * hinvL;
        const int ro = (cbase + jc * 16 + l15) * DD;
        const i32x4 lo = *(const i32x4*)&Bs[ro + (((q << 1) | 0) ^ xr) * 16];
        const i32x4 hi = *(const i32x4*)&Bs[ro + (((q << 1) | 1) ^ xr) * 16];
        #pragma unroll
        for (int e = 0; e < 4; ++e) { b8v[jc][e] = lo[e]; b8v[jc][4 + e] = hi[e]; }
    }
    // hoisted per-thread max of the c-side term (for the underflow bound)
    float nbmax = fmaxf(fmaxf(fmaxf(nbh[0][0], nbh[0][1]), fmaxf(nbh[0][2], nbh[0][3])),
                        fmaxf(fmaxf(nbh[1][0], nbh[1][1]), fmaxf(nbh[1][2], nbh[1][3])));
    nbmax = fmaxf(nbmax,
                  fmaxf(fmaxf(fmaxf(nbh[2][0], nbh[2][1]), fmaxf(nbh[2][2], nbh[2][3])),
                        fmaxf(fmaxf(nbh[3][0], nbh[3][1]), fmaxf(nbh[3][2], nbh[3][3]))));

    // A fragments: lane holds A[rbase+i*16+l15][q*32 .. q*32+31]
    i32x8 a8[4];
    #pragma unroll
    for (int i = 0; i < 4; ++i) {
        const int ro = (rbase + i * 16 + l15) * DD;
        const i32x4 lo = *(const i32x4*)&As[ro + (((q << 1) | 0) ^ xr) * 16];
        const i32x4 hi = *(const i32x4*)&As[ro + (((q << 1) | 1) ^ xr) * 16];
        #pragma unroll
        for (int e = 0; e < 4; ++e) { a8[i][e] = lo[e]; a8[i][4 + e] = hi[e]; }
    }

    // Swapped operands -> c-reduction in-register. 16 MFMAs, pure-register.
    f32x4 acc[4][4] = {};
    __builtin_amdgcn_s_setprio(1);
    #pragma unroll
    for (int jc = 0; jc < 4; ++jc)
        #pragma unroll
        for (int i = 0; i < 4; ++i)
            acc[jc][i] = __builtin_amdgcn_mfma_scale_f32_16x16x128_f8f6f4(
                            b8v[jc], a8[i], acc[jc][i],
                            0, 0,          // cbsz=0 (fp8), blgp=0 (fp8)
                            0, 127,        // scale_a = 1.0
                            0, 127);       // scale_b = 1.0
    __builtin_amdgcn_s_setprio(0);

    // per-i a2 terms (needed by both paths)
    float aih[4];
    #pragma unroll
    for (int i = 0; i < 4; ++i) aih[i] = a2s[rbase + i * 16 + l15] * hinvL;
    const float aihmin = fminf(fminf(aih[0], aih[1]), fminf(aih[2], aih[3]));

    // wave-level max of all 64 acc values: nested triples -> v_max3 tree
    f32x4 vm[4];
    #pragma unroll
    for (int jc = 0; jc < 4; ++jc)
        vm[jc] = __builtin_elementwise_max(
                     __builtin_elementwise_max(acc[jc][0], acc[jc][1]),
                     __builtin_elementwise_max(acc[jc][2], acc[jc][3]));
    const f32x4 vmx = __builtin_elementwise_max(
                          __builtin_elementwise_max(vm[0], vm[1]),
                          __builtin_elementwise_max(vm[2], vm[3]));
    const float mxall = fmaxf(fmaxf(vmx[0], vmx[1]), fmaxf(vmx[2], vmx[3]));

    // exact skip: bound >= every exp2 arg in this wave's 4x16 block
    if (__any(fmaf(h2L, mxall, nbmax - aihmin) > -126.f)) {
        // full epilogue (byte-identical to verified R15 non-skip path)
        float sums[4];
        #pragma unroll
        for (int i = 0; i < 4; ++i) {
            float s0 = 0.f, s1 = 0.f;
            #pragma unroll
            for (int jc = 0; jc < 4; jc += 2) {
                #pragma unroll
                for (int r = 0; r < 4; ++r) {
                    s0 += __builtin_amdgcn_exp2f(fmaf(h2L, acc[jc][i][r],     nbh[jc][r]     - aih[i]));
                    s1 += __builtin_amdgcn_exp2f(fmaf(h2L, acc[jc + 1][i][r], nbh[jc + 1][r] - aih[i]));
                }
            }
            float s = s0 + s1;
            s += __shfl_xor(s, 16, 64);
            s += __shfl_xor(s, 32, 64);
            sums[i] = s;
        }
        const float v01 = (q & 1) ? sums[1] : sums[0];
        const float v23 = (q & 1) ? sums[3] : sums[2];
        const float myv = (q & 2) ? v23 : v01;
        dpc[(size_t)m * NN + n0 + rbase + lane] = myv;
    } else {
        // all 64 exps underflow to +0.0f: sums are exactly 0 for every lane
        dpc[(size_t)m * NN + n0 + rbase + lane] = 0.f;
    }
}

// ---- normalize: out[n,m] = dpc[m,n] / (sum_m dpc[:,n] + 1e-10) ----
// 256 blocks x 16 n each; m-ascending sum order matches reference.
__global__ __launch_bounds__(256)
void kde_norm_kernel(const float* __restrict__ dpc, float* __restrict__ out)
{
    __shared__ float tile[128][17];    // [m][nloc], odd stride
    __shared__ float rden[16];
    const int n0 = blockIdx.x * 16;
    const int t  = threadIdx.x;

    const int mr = t >> 1, half = t & 1;   // 128 rows x 2 threads
    {
        const float4 va = *(const float4*)&dpc[(size_t)mr * NN + n0 + half * 8];
        const float4 vb = *(const float4*)&dpc[(size_t)mr * NN + n0 + half * 8 + 4];
        float* tr = &tile[mr][half * 8];
        tr[0] = va.x; tr[1] = va.y; tr[2] = va.z; tr[3] = va.w;
        tr[4] = vb.x; tr[5] = vb.y; tr[6] = vb.z; tr[7] = vb.w;
    }
    __syncthreads();

    if (t < 16) {
        float s = 0.f;
        #pragma unroll 8
        for (int mm = 0; mm < MM; ++mm) s += tile[mm][t];   // m ascending, matches ref
        rden[t] = 1.f / (s + 1e-10f);
    }
    __syncthreads();

    const int j = t >> 4, m0 = (t & 15) * 8;
    const float r = rden[j];
    float4 o0, o1;
    o0.x = tile[m0][j] * r;     o0.y = tile[m0 + 1][j] * r;
    o0.z = tile[m0 + 2][j] * r; o0.w = tile[m0 + 3][j] * r;
    o1.x = tile[m0 + 4][j] * r; o1.y = tile[m0 + 5][j] * r;
    o1.z = tile[m0 + 6][j] * r; o1.w = tile[m0 + 7][j] * r;
    float* obase = &out[(size_t)(n0 + j) * MM + m0];
    *(float4*)obase       = o0;
    *(float4*)(obase + 4) = o1;   // 512B per 16-thread group, coalesced
}

extern "C" void kernel_launch(void* const* d_in, const int* in_sizes, int n_in,
                              void* d_out, int out_size, void* d_ws, size_t ws_size,
                              hipStream_t stream) {
    const float* A   = (const float*)d_in[0];   // [4096][128]
    const float* B   = (const float*)d_in[1];   // [128][64][128] = [8192][128]
    const float* var = (const float*)d_in[2];   // [1]
    float* out = (float*)d_out;                 // [4096][128]

    unsigned char* A8 = (unsigned char*)d_ws;            // 512 KB
    unsigned char* B8 = A8 + (size_t)NN * DD;            // 1 MB
    float* a2  = (float*)(B8 + (size_t)CC * DD);         // 16 KB
    float* b2  = a2 + NN;                                // 32 KB
    float* dpc = b2 + CC;                                // 2 MB, [MM][NN]

    prep_kernel<<<(NN + CC) / 8, 256, 0, stream>>>(A, B, A8, B8, a2, b2);
    kde_dens_kernel<<<2048, 256, 0, stream>>>(A8, B8, var, a2, b2, dpc);
    kde_norm_kernel<<<NN / 16, 256, 0, stream>>>(dpc, out);
}